// Round 2
// baseline (2347.000 us; speedup 1.0000x reference)
//
#include <hip/hip_runtime.h>
#include <hip/hip_bf16.h>
#include <math.h>

// Problem constants
constexpr int Bb = 8, Ss = 128, Dd = 512, Vv = 32768, Hh = 8, Pp = 2048, Ll = 4, STEPS = 3;
constexpr int Tt = Bb * Ss;          // 1024 tokens
constexpr int DK = Dd / Hh;          // 64
constexpr float SCALE = 0.125f;      // 1/sqrt(64)

// ---------------------------------------------------------------------------
// Embedding gather: X[t][d] = emb[tokens[t]][d]
__global__ __launch_bounds__(128) void embed_k(const int* __restrict__ tokens,
                                               const float* __restrict__ emb,
                                               float* __restrict__ X) {
    int t = blockIdx.x;
    int tok = tokens[t];
    const float4* src = reinterpret_cast<const float4*>(emb + (long)tok * Dd);
    float4* dst = reinterpret_cast<float4*>(X + (long)t * Dd);
    dst[threadIdx.x] = src[threadIdx.x];
}

// ---------------------------------------------------------------------------
// Generic SGEMM: C[M,N] = A[M,K] @ W[N,K]^T + b1[N] (+ b2[N]) (+ ReLU)
// Both A and W are row-major with K contiguous (NT gemm).
template <int RELU>
__global__ __launch_bounds__(256) void sgemm_nt(const float* __restrict__ A,
                                                const float* __restrict__ W,
                                                const float* __restrict__ b1,
                                                const float* __restrict__ b2,
                                                float* __restrict__ C,
                                                int M, int N, int K) {
    constexpr int BM = 64, BN = 64, BK = 16, PITCH = BM + 4; // 16B-aligned rows, bank-spread
    __shared__ float As[BK][PITCH];
    __shared__ float Ws[BK][PITCH];

    const int tid = threadIdx.x;
    const int tx = tid & 15, ty = tid >> 4;
    const int row0 = blockIdx.y * BM, col0 = blockIdx.x * BN;

    const int lr = tid >> 2;            // 0..63: row within tile
    const int lk4 = (tid & 3) * 4;      // float4 col offset within BK

    float acc[4][4] = {};

    for (int k0 = 0; k0 < K; k0 += BK) {
        float4 av = *reinterpret_cast<const float4*>(&A[(long)(row0 + lr) * K + k0 + lk4]);
        float4 wv = *reinterpret_cast<const float4*>(&W[(long)(col0 + lr) * K + k0 + lk4]);
        As[lk4 + 0][lr] = av.x; As[lk4 + 1][lr] = av.y;
        As[lk4 + 2][lr] = av.z; As[lk4 + 3][lr] = av.w;
        Ws[lk4 + 0][lr] = wv.x; Ws[lk4 + 1][lr] = wv.y;
        Ws[lk4 + 2][lr] = wv.z; Ws[lk4 + 3][lr] = wv.w;
        __syncthreads();
#pragma unroll
        for (int k = 0; k < BK; ++k) {
            float ar[4], wr[4];
#pragma unroll
            for (int i = 0; i < 4; ++i) { ar[i] = As[k][ty * 4 + i]; wr[i] = Ws[k][tx * 4 + i]; }
#pragma unroll
            for (int i = 0; i < 4; ++i)
#pragma unroll
                for (int j = 0; j < 4; ++j) acc[i][j] += ar[i] * wr[j];
        }
        __syncthreads();
    }

    const int cbase = col0 + tx * 4;
    float bb[4];
#pragma unroll
    for (int j = 0; j < 4; ++j) {
        bb[j] = b1[cbase + j];
        if (b2) bb[j] += b2[cbase + j];
    }
#pragma unroll
    for (int i = 0; i < 4; ++i) {
        int r = row0 + ty * 4 + i;
        float4 v;
        v.x = acc[i][0] + bb[0];
        v.y = acc[i][1] + bb[1];
        v.z = acc[i][2] + bb[2];
        v.w = acc[i][3] + bb[3];
        if (RELU) {
            v.x = fmaxf(v.x, 0.f); v.y = fmaxf(v.y, 0.f);
            v.z = fmaxf(v.z, 0.f); v.w = fmaxf(v.w, 0.f);
        }
        *reinterpret_cast<float4*>(&C[(long)r * N + cbase]) = v;
    }
}

// ---------------------------------------------------------------------------
// Attention: one wave per (b,h,query-row). qkv rows are 3D wide: [q | k | v].
__global__ __launch_bounds__(64) void attn_k(const float* __restrict__ qkv,
                                             float* __restrict__ O) {
    const int id = blockIdx.x;             // b*H*S + h*S + r
    const int r = id % Ss;
    const int bh = id / Ss;
    const int h = bh % Hh;
    const int b = bh / Hh;
    const int lane = threadIdx.x;

    const long rowpitch = 3 * Dd;
    const float* qrow = qkv + (long)(b * Ss + r) * rowpitch + h * DK;
    const int c0 = lane, c1 = lane + 64;
    const float* k0p = qkv + (long)(b * Ss + c0) * rowpitch + Dd + h * DK;
    const float* k1p = qkv + (long)(b * Ss + c1) * rowpitch + Dd + h * DK;

    float s0 = 0.f, s1 = 0.f;
    for (int d = 0; d < DK; ++d) {
        float qd = qrow[d];
        s0 += qd * k0p[d];
        s1 += qd * k1p[d];
    }
    s0 *= SCALE; s1 *= SCALE;
    if (c0 > r) s0 = -INFINITY;
    if (c1 > r) s1 = -INFINITY;

    float mx = fmaxf(s0, s1);
    for (int off = 1; off < 64; off <<= 1) mx = fmaxf(mx, __shfl_xor(mx, off));
    float e0 = (c0 <= r) ? expf(s0 - mx) : 0.f;
    float e1 = (c1 <= r) ? expf(s1 - mx) : 0.f;
    float sum = e0 + e1;
    for (int off = 1; off < 64; off <<= 1) sum += __shfl_xor(sum, off);
    float inv = 1.f / sum;

    __shared__ float p[Ss];
    p[c0] = e0 * inv;
    p[c1] = e1 * inv;
    __syncthreads();

    // phase 2: lane = head dim
    const float* vbase = qkv + (long)(b * Ss) * rowpitch + 2 * Dd + h * DK + lane;
    float o = 0.f;
    for (int c = 0; c <= r; ++c) o += p[c] * vbase[(long)c * rowpitch];
    O[(long)(b * Ss + r) * Dd + h * DK + lane] = o;
}

// ---------------------------------------------------------------------------
// out = LayerNorm(a + bsrc) * w + bias   (row = one block, 256 thr, 2 elems ea)
__global__ __launch_bounds__(256) void add_ln_k(float* __restrict__ out,
                                                const float* __restrict__ a,
                                                const float* __restrict__ bsrc,
                                                const float* __restrict__ w,
                                                const float* __restrict__ bias) {
    const int t = blockIdx.x;
    const int tid = threadIdx.x;
    float2 av = *reinterpret_cast<const float2*>(&a[(long)t * Dd + tid * 2]);
    float2 bv = *reinterpret_cast<const float2*>(&bsrc[(long)t * Dd + tid * 2]);
    float x0 = av.x + bv.x, x1 = av.y + bv.y;
    float s = x0 + x1, ss = x0 * x0 + x1 * x1;
    for (int off = 1; off < 64; off <<= 1) {
        s += __shfl_xor(s, off);
        ss += __shfl_xor(ss, off);
    }
    __shared__ float sm[4], ssm[4];
    int wid = tid >> 6;
    if ((tid & 63) == 0) { sm[wid] = s; ssm[wid] = ss; }
    __syncthreads();
    s = sm[0] + sm[1] + sm[2] + sm[3];
    ss = ssm[0] + ssm[1] + ssm[2] + ssm[3];
    float mean = s * (1.f / Dd);
    float var = ss * (1.f / Dd) - mean * mean;
    float rstd = rsqrtf(var + 1e-5f);
    out[(long)t * Dd + tid * 2]     = (x0 - mean) * rstd * w[tid * 2] + bias[tid * 2];
    out[(long)t * Dd + tid * 2 + 1] = (x1 - mean) * rstd * w[tid * 2 + 1] + bias[tid * 2 + 1];
}

// ---------------------------------------------------------------------------
// LSTM elementwise: gates rows are 4D wide [i|f|g|o]; torch gate order.
__global__ __launch_bounds__(256) void lstm_ew_k(const float* __restrict__ gates,
                                                 float* __restrict__ h,
                                                 float* __restrict__ c,
                                                 int first) {
    int idx = blockIdx.x * 256 + threadIdx.x;   // over T*D
    int t = idx >> 9;   // /512
    int d = idx & 511;
    const float* g = gates + (long)t * (4 * Dd);
    float ig = g[d], fg = g[Dd + d], gg = g[2 * Dd + d], og = g[3 * Dd + d];
    float si = 1.f / (1.f + expf(-ig));
    float sf = 1.f / (1.f + expf(-fg));
    float so = 1.f / (1.f + expf(-og));
    float cold = first ? 0.f : c[idx];
    float cn = sf * cold + si * tanhf(gg);
    float hn = so * tanhf(cn);
    c[idx] = cn;
    h[idx] = hn;
}

// out = a + b (float4)
__global__ __launch_bounds__(256) void add_k(float* __restrict__ out,
                                             const float* __restrict__ a,
                                             const float* __restrict__ b) {
    int i = blockIdx.x * 256 + threadIdx.x;
    const float4 av = reinterpret_cast<const float4*>(a)[i];
    const float4 bv = reinterpret_cast<const float4*>(b)[i];
    float4 o;
    o.x = av.x + bv.x; o.y = av.y + bv.y; o.z = av.z + bv.z; o.w = av.w + bv.w;
    reinterpret_cast<float4*>(out)[i] = o;
}

// ---------------------------------------------------------------------------
extern "C" void kernel_launch(void* const* d_in, const int* in_sizes, int n_in,
                              void* d_out, int out_size, void* d_ws, size_t ws_size,
                              hipStream_t stream) {
    const int*   tokens     = (const int*)  d_in[0];
    const float* emb        = (const float*)d_in[1];
    const float* in_proj_w  = (const float*)d_in[2];
    const float* in_proj_b  = (const float*)d_in[3];
    const float* attn_out_w = (const float*)d_in[4];
    const float* attn_out_b = (const float*)d_in[5];
    const float* ln1_w      = (const float*)d_in[6];
    const float* ln1_b      = (const float*)d_in[7];
    const float* lstm_wih   = (const float*)d_in[8];
    const float* lstm_whh   = (const float*)d_in[9];
    const float* lstm_bih   = (const float*)d_in[10];
    const float* lstm_bhh   = (const float*)d_in[11];
    const float* ff_w1      = (const float*)d_in[12];
    const float* ff_b1      = (const float*)d_in[13];
    const float* ff_w2      = (const float*)d_in[14];
    const float* ff_b2      = (const float*)d_in[15];
    const float* ln2_w      = (const float*)d_in[16];
    const float* ln2_b      = (const float*)d_in[17];
    const float* head_w     = (const float*)d_in[18];
    const float* head_b     = (const float*)d_in[19];
    float* out = (float*)d_out;

    // workspace layout (floats)
    float* ws   = (float*)d_ws;
    const long TD = (long)Tt * Dd;          // 524288
    float* X    = ws;
    float* Hb   = X + TD;
    float* Cb   = Hb + TD;
    float* LAT  = Cb + TD;
    float* Ta   = LAT + TD;
    float* Tb   = Ta + TD;
    float* BIG  = Tb + TD;                  // 1024 x 2048
    float* WSUM = BIG + (long)Tt * 2048;    // 2048 x 512

    embed_k<<<Tt, 128, 0, stream>>>(tokens, emb, X);

    for (int l = 0; l < Ll; ++l) {
        // --- attention ---
        sgemm_nt<0><<<dim3(3 * Dd / 64, Tt / 64), 256, 0, stream>>>(
            X, in_proj_w + (long)l * 3 * Dd * Dd, in_proj_b + (long)l * 3 * Dd, nullptr,
            BIG, Tt, 3 * Dd, Dd);
        attn_k<<<Bb * Hh * Ss, 64, 0, stream>>>(BIG, Ta);
        sgemm_nt<0><<<dim3(Dd / 64, Tt / 64), 256, 0, stream>>>(
            Ta, attn_out_w + (long)l * Dd * Dd, attn_out_b + (long)l * Dd, nullptr,
            Tb, Tt, Dd, Dd);
        add_ln_k<<<Tt, 256, 0, stream>>>(X, X, Tb, ln1_w + (long)l * Dd, ln1_b + (long)l * Dd);

        // --- LSTM latent recurrence ---
        // wsum = wih + whh (steps 2..3 have latent == h)
        add_k<<<(4 * Dd * Dd) / 4 / 256, 256, 0, stream>>>(
            WSUM, lstm_wih + (long)l * 4 * Dd * Dd, lstm_whh + (long)l * 4 * Dd * Dd);
        const float* bih = lstm_bih + (long)l * 4 * Dd;
        const float* bhh = lstm_bhh + (long)l * 4 * Dd;
        // step 1: h=0, c=0
        sgemm_nt<0><<<dim3(4 * Dd / 64, Tt / 64), 256, 0, stream>>>(
            X, lstm_wih + (long)l * 4 * Dd * Dd, bih, bhh, BIG, Tt, 4 * Dd, Dd);
        lstm_ew_k<<<(Tt * Dd) / 256, 256, 0, stream>>>(BIG, Hb, Cb, 1);
        // steps 2..3
        for (int s = 1; s < STEPS; ++s) {
            sgemm_nt<0><<<dim3(4 * Dd / 64, Tt / 64), 256, 0, stream>>>(
                Hb, WSUM, bih, bhh, BIG, Tt, 4 * Dd, Dd);
            lstm_ew_k<<<(Tt * Dd) / 256, 256, 0, stream>>>(BIG, Hb, Cb, 0);
        }
        // latent = residual + h
        add_k<<<(int)(TD / 4 / 256), 256, 0, stream>>>(LAT, X, Hb);

        // --- feed forward ---
        sgemm_nt<1><<<dim3(Pp / 64, Tt / 64), 256, 0, stream>>>(
            LAT, ff_w1 + (long)l * Pp * Dd, ff_b1 + (long)l * Pp, nullptr, BIG, Tt, Pp, Dd);
        sgemm_nt<0><<<dim3(Dd / 64, Tt / 64), 256, 0, stream>>>(
            BIG, ff_w2 + (long)l * Dd * Pp, ff_b2 + (long)l * Dd, nullptr, Ta, Tt, Dd, Pp);
        add_ln_k<<<Tt, 256, 0, stream>>>(X, LAT, Ta, ln2_w + (long)l * Dd, ln2_b + (long)l * Dd);
    }

    // --- head ---
    sgemm_nt<0><<<dim3(Vv / 64, Tt / 64), 256, 0, stream>>>(
        X, head_w, head_b, nullptr, out, Tt, Vv, Dd);
}

// Round 3
// 975.542 us; speedup vs baseline: 2.4058x; 2.4058x over previous
//
#include <hip/hip_runtime.h>
#include <hip/hip_bf16.h>
#include <math.h>

typedef unsigned short ushort_t;
typedef __bf16 bf16x8 __attribute__((ext_vector_type(8)));
typedef float f32x4 __attribute__((ext_vector_type(4)));

// Problem constants
constexpr int Bb = 8, Ss = 128, Dd = 512, Vv = 32768, Hh = 8, Pp = 2048, Ll = 4, STEPS = 3;
constexpr int Tt = Bb * Ss;          // 1024 tokens
constexpr int DK = Dd / Hh;          // 64
constexpr float SCALE = 0.125f;      // 1/sqrt(64)

// fp32 -> bf16 RNE
__device__ __forceinline__ ushort_t f2b(float f) {
    unsigned u = __float_as_uint(f);
    unsigned r = (u + 0x7FFFu + ((u >> 16) & 1u)) >> 16;
    return (ushort_t)r;
}

__device__ __forceinline__ void gload_lds16(const void* g, void* l) {
    __builtin_amdgcn_global_load_lds((const __attribute__((address_space(1))) void*)g,
                                     (__attribute__((address_space(3))) void*)l, 16, 0, 0);
}

// ---------------------------------------------------------------------------
// f32 -> bf16 conversion (vectorized, n multiple of 1024)
__global__ __launch_bounds__(256) void cvt_k(const float* __restrict__ src,
                                             ushort_t* __restrict__ dst) {
    int i = blockIdx.x * 256 + threadIdx.x;
    float4 v = reinterpret_cast<const float4*>(src)[i];
    ushort4 o;
    o.x = f2b(v.x); o.y = f2b(v.y); o.z = f2b(v.z); o.w = f2b(v.w);
    reinterpret_cast<ushort4*>(dst)[i] = o;
}

// dst_bf16 = a + b  (for wsum = wih + whh)
__global__ __launch_bounds__(256) void cvtadd_k(const float* __restrict__ a,
                                                const float* __restrict__ b,
                                                ushort_t* __restrict__ dst) {
    int i = blockIdx.x * 256 + threadIdx.x;
    float4 va = reinterpret_cast<const float4*>(a)[i];
    float4 vb = reinterpret_cast<const float4*>(b)[i];
    ushort4 o;
    o.x = f2b(va.x + vb.x); o.y = f2b(va.y + vb.y);
    o.z = f2b(va.z + vb.z); o.w = f2b(va.w + vb.w);
    reinterpret_cast<ushort4*>(dst)[i] = o;
}

// ---------------------------------------------------------------------------
// Embedding gather: X[t][d] = emb[tokens[t]][d] (f32 + bf16)
__global__ __launch_bounds__(128) void embed_k(const int* __restrict__ tokens,
                                               const float* __restrict__ emb,
                                               float* __restrict__ X,
                                               ushort_t* __restrict__ Xb) {
    int t = blockIdx.x;
    int tok = tokens[t];
    float4 v = reinterpret_cast<const float4*>(emb + (long)tok * Dd)[threadIdx.x];
    reinterpret_cast<float4*>(X + (long)t * Dd)[threadIdx.x] = v;
    ushort4 o;
    o.x = f2b(v.x); o.y = f2b(v.y); o.z = f2b(v.z); o.w = f2b(v.w);
    reinterpret_cast<ushort4*>(Xb + (long)t * Dd)[threadIdx.x] = o;
}

// ---------------------------------------------------------------------------
// bf16 MFMA GEMM: C[M,N] = A[M,K] @ W[N,K]^T + b1[N] (+b2[N]) (+ReLU)
// A, W bf16 row-major (K contiguous). 256 thr = 4 waves (2x2), tile BMxBN.
// LDS staged via global_load_lds (linear dest) with both-sides XOR swizzle.
template <int BM, int BN, int BK, int RELU, int BOUT>
__global__ __launch_bounds__(256) void gemm_bf16(const ushort_t* __restrict__ A,
                                                 const ushort_t* __restrict__ W,
                                                 const float* __restrict__ b1,
                                                 const float* __restrict__ b2,
                                                 float* __restrict__ C,
                                                 ushort_t* __restrict__ Cb,
                                                 int M, int N, int K) {
    constexpr int CH = BK / 8;                 // 16B chunks per row
    constexpr int SH = (CH == 4) ? 1 : 0;      // swizzle row shift (bank period)
    constexpr int WM = BM / 2, WN = BN / 2;    // wave sub-tile
    constexpr int FM = WM / 16, FN = WN / 16;  // 16x16 fragments per wave
    constexpr int LA = BM * BK / 2048;         // 16B loads per thread per tile
    constexpr int LW = BN * BK / 2048;

    __shared__ __align__(16) ushort_t As[BM * BK];
    __shared__ __align__(16) ushort_t Ws[BN * BK];

    const int tid = threadIdx.x;
    const int lane = tid & 63, wid = tid >> 6;
    const int wr = wid >> 1, wc = wid & 1;
    const int row0 = blockIdx.y * BM, col0 = blockIdx.x * BN;

    f32x4 acc[FM][FN];
#pragma unroll
    for (int m = 0; m < FM; ++m)
#pragma unroll
        for (int n = 0; n < FN; ++n) acc[m][n] = (f32x4)(0.0f);

    for (int k0 = 0; k0 < K; k0 += BK) {
        // stage A tile: LDS linear; global source pre-swizzled (rule #21)
#pragma unroll
        for (int i = 0; i < LA; ++i) {
            int j = i * 256 + tid;                 // chunk id in tile
            int prow = j >> (CH == 4 ? 2 : 3);
            int pkg = j & (CH - 1);
            int skg = pkg ^ ((prow >> SH) & (CH - 1));
            gload_lds16(A + (long)(row0 + prow) * K + k0 + skg * 8,
                        &As[(i * 256 + wid * 64) * 8]);
        }
#pragma unroll
        for (int i = 0; i < LW; ++i) {
            int j = i * 256 + tid;
            int prow = j >> (CH == 4 ? 2 : 3);
            int pkg = j & (CH - 1);
            int skg = pkg ^ ((prow >> SH) & (CH - 1));
            gload_lds16(W + (long)(col0 + prow) * K + k0 + skg * 8,
                        &Ws[(i * 256 + wid * 64) * 8]);
        }
        __syncthreads();

#pragma unroll
        for (int kk = 0; kk < BK / 32; ++kk) {
            bf16x8 af[FM], wf[FN];
#pragma unroll
            for (int m = 0; m < FM; ++m) {
                int r = wr * WM + m * 16 + (lane & 15);
                int cl = kk * 4 + (lane >> 4);
                int cs = cl ^ ((r >> SH) & (CH - 1));
                af[m] = *reinterpret_cast<const bf16x8*>(&As[r * BK + cs * 8]);
            }
#pragma unroll
            for (int n = 0; n < FN; ++n) {
                int r = wc * WN + n * 16 + (lane & 15);
                int cl = kk * 4 + (lane >> 4);
                int cs = cl ^ ((r >> SH) & (CH - 1));
                wf[n] = *reinterpret_cast<const bf16x8*>(&Ws[r * BK + cs * 8]);
            }
#pragma unroll
            for (int m = 0; m < FM; ++m)
#pragma unroll
                for (int n = 0; n < FN; ++n)
                    acc[m][n] = __builtin_amdgcn_mfma_f32_16x16x32_bf16(
                        af[m], wf[n], acc[m][n], 0, 0, 0);
        }
        __syncthreads();
    }

    // epilogue: C/D layout col=lane&15, row=(lane>>4)*4+j (m89-verified)
#pragma unroll
    for (int n = 0; n < FN; ++n) {
        int col = col0 + wc * WN + n * 16 + (lane & 15);
        float bias = b1[col];
        if (b2) bias += b2[col];
#pragma unroll
        for (int m = 0; m < FM; ++m) {
#pragma unroll
            for (int j = 0; j < 4; ++j) {
                int row = row0 + wr * WM + m * 16 + (lane >> 4) * 4 + j;
                float v = acc[m][n][j] + bias;
                if (RELU) v = fmaxf(v, 0.f);
                if (BOUT) Cb[(long)row * N + col] = f2b(v);
                else      C[(long)row * N + col] = v;
            }
        }
    }
}

// ---------------------------------------------------------------------------
// Attention: one wave per (b,h,query-row). qkv rows are 3D wide: [q | k | v].
// Output written bf16 only (feeds out-proj GEMM).
__global__ __launch_bounds__(64) void attn_k(const float* __restrict__ qkv,
                                             ushort_t* __restrict__ Ob) {
    const int id = blockIdx.x;             // b*H*S + h*S + r
    const int r = id % Ss;
    const int bh = id / Ss;
    const int h = bh % Hh;
    const int b = bh / Hh;
    const int lane = threadIdx.x;

    const long rowpitch = 3 * Dd;
    const float* qrow = qkv + (long)(b * Ss + r) * rowpitch + h * DK;
    const int c0 = lane, c1 = lane + 64;
    const float* k0p = qkv + (long)(b * Ss + c0) * rowpitch + Dd + h * DK;
    const float* k1p = qkv + (long)(b * Ss + c1) * rowpitch + Dd + h * DK;

    float s0 = 0.f, s1 = 0.f;
    for (int d = 0; d < DK; ++d) {
        float qd = qrow[d];
        s0 += qd * k0p[d];
        s1 += qd * k1p[d];
    }
    s0 *= SCALE; s1 *= SCALE;
    if (c0 > r) s0 = -INFINITY;
    if (c1 > r) s1 = -INFINITY;

    float mx = fmaxf(s0, s1);
    for (int off = 1; off < 64; off <<= 1) mx = fmaxf(mx, __shfl_xor(mx, off));
    float e0 = (c0 <= r) ? expf(s0 - mx) : 0.f;
    float e1 = (c1 <= r) ? expf(s1 - mx) : 0.f;
    float sum = e0 + e1;
    for (int off = 1; off < 64; off <<= 1) sum += __shfl_xor(sum, off);
    float inv = 1.f / sum;

    __shared__ float p[Ss];
    p[c0] = e0 * inv;
    p[c1] = e1 * inv;
    __syncthreads();

    const float* vbase = qkv + (long)(b * Ss) * rowpitch + 2 * Dd + h * DK + lane;
    float o = 0.f;
    for (int c = 0; c <= r; ++c) o += p[c] * vbase[(long)c * rowpitch];
    Ob[(long)(b * Ss + r) * Dd + h * DK + lane] = f2b(o);
}

// ---------------------------------------------------------------------------
// out = LayerNorm(a + bsrc) * w + bias  -> f32 + bf16
__global__ __launch_bounds__(256) void add_ln_k(float* __restrict__ out,
                                                ushort_t* __restrict__ outb,
                                                const float* __restrict__ a,
                                                const float* __restrict__ bsrc,
                                                const float* __restrict__ w,
                                                const float* __restrict__ bias) {
    const int t = blockIdx.x;
    const int tid = threadIdx.x;
    float2 av = *reinterpret_cast<const float2*>(&a[(long)t * Dd + tid * 2]);
    float2 bv = *reinterpret_cast<const float2*>(&bsrc[(long)t * Dd + tid * 2]);
    float x0 = av.x + bv.x, x1 = av.y + bv.y;
    float s = x0 + x1, ss = x0 * x0 + x1 * x1;
    for (int off = 1; off < 64; off <<= 1) {
        s += __shfl_xor(s, off);
        ss += __shfl_xor(ss, off);
    }
    __shared__ float sm[4], ssm[4];
    int wid = tid >> 6;
    if ((tid & 63) == 0) { sm[wid] = s; ssm[wid] = ss; }
    __syncthreads();
    s = sm[0] + sm[1] + sm[2] + sm[3];
    ss = ssm[0] + ssm[1] + ssm[2] + ssm[3];
    float mean = s * (1.f / Dd);
    float var = ss * (1.f / Dd) - mean * mean;
    float rstd = rsqrtf(var + 1e-5f);
    float o0 = (x0 - mean) * rstd * w[tid * 2] + bias[tid * 2];
    float o1 = (x1 - mean) * rstd * w[tid * 2 + 1] + bias[tid * 2 + 1];
    out[(long)t * Dd + tid * 2]     = o0;
    out[(long)t * Dd + tid * 2 + 1] = o1;
    ushort2 ob; ob.x = f2b(o0); ob.y = f2b(o1);
    *reinterpret_cast<ushort2*>(&outb[(long)t * Dd + tid * 2]) = ob;
}

// ---------------------------------------------------------------------------
// LSTM elementwise: gates rows 4D wide [i|f|g|o]; h written f32 + bf16.
__global__ __launch_bounds__(256) void lstm_ew_k(const float* __restrict__ gates,
                                                 float* __restrict__ h,
                                                 ushort_t* __restrict__ hb,
                                                 float* __restrict__ c,
                                                 int first) {
    int idx = blockIdx.x * 256 + threadIdx.x;   // over T*D
    int t = idx >> 9;
    int d = idx & 511;
    const float* g = gates + (long)t * (4 * Dd);
    float ig = g[d], fg = g[Dd + d], gg = g[2 * Dd + d], og = g[3 * Dd + d];
    float si = 1.f / (1.f + expf(-ig));
    float sf = 1.f / (1.f + expf(-fg));
    float so = 1.f / (1.f + expf(-og));
    float cold = first ? 0.f : c[idx];
    float cn = sf * cold + si * tanhf(gg);
    float hn = so * tanhf(cn);
    c[idx] = cn;
    h[idx] = hn;
    hb[idx] = f2b(hn);
}

// out = a + b -> f32 + bf16
__global__ __launch_bounds__(256) void add_k(float* __restrict__ out,
                                             ushort_t* __restrict__ outb,
                                             const float* __restrict__ a,
                                             const float* __restrict__ b) {
    int i = blockIdx.x * 256 + threadIdx.x;
    const float4 av = reinterpret_cast<const float4*>(a)[i];
    const float4 bv = reinterpret_cast<const float4*>(b)[i];
    float4 o;
    o.x = av.x + bv.x; o.y = av.y + bv.y; o.z = av.z + bv.z; o.w = av.w + bv.w;
    reinterpret_cast<float4*>(out)[i] = o;
    ushort4 ob;
    ob.x = f2b(o.x); ob.y = f2b(o.y); ob.z = f2b(o.z); ob.w = f2b(o.w);
    reinterpret_cast<ushort4*>(outb)[i] = ob;
}

// ---------------------------------------------------------------------------
extern "C" void kernel_launch(void* const* d_in, const int* in_sizes, int n_in,
                              void* d_out, int out_size, void* d_ws, size_t ws_size,
                              hipStream_t stream) {
    const int*   tokens     = (const int*)  d_in[0];
    const float* emb        = (const float*)d_in[1];
    const float* in_proj_w  = (const float*)d_in[2];
    const float* in_proj_b  = (const float*)d_in[3];
    const float* attn_out_w = (const float*)d_in[4];
    const float* attn_out_b = (const float*)d_in[5];
    const float* ln1_w      = (const float*)d_in[6];
    const float* ln1_b      = (const float*)d_in[7];
    const float* lstm_wih   = (const float*)d_in[8];
    const float* lstm_whh   = (const float*)d_in[9];
    const float* lstm_bih   = (const float*)d_in[10];
    const float* lstm_bhh   = (const float*)d_in[11];
    const float* ff_w1      = (const float*)d_in[12];
    const float* ff_b1      = (const float*)d_in[13];
    const float* ff_w2      = (const float*)d_in[14];
    const float* ff_b2      = (const float*)d_in[15];
    const float* ln2_w      = (const float*)d_in[16];
    const float* ln2_b      = (const float*)d_in[17];
    const float* head_w     = (const float*)d_in[18];
    const float* head_bias  = (const float*)d_in[19];
    float* out = (float*)d_out;

    // ---- workspace layout (total = 100 MB) ----
    const long TD = (long)Tt * Dd;          // 524288
    float* ws   = (float*)d_ws;
    float* X    = ws;
    float* Hb   = X + TD;
    float* Cb   = Hb + TD;
    float* LAT  = Cb + TD;
    float* Ta   = LAT + TD;                 // ffn2 out
    float* Tb   = Ta + TD;                  // out-proj out
    float* BIG  = Tb + TD;                  // 1024 x 2048 (qkv / gates / ffn1)
    ushort_t* Xb    = (ushort_t*)(BIG + (long)Tt * 2048);
    ushort_t* Hbb   = Xb + TD;
    ushort_t* LATb  = Hbb + TD;
    ushort_t* Tab   = LATb + TD;
    ushort_t* BIGb  = Tab + TD;             // 1024 x 2048
    ushort_t* ipw   = BIGb + (long)Tt * 2048;   // 4 x 1536 x 512
    ushort_t* aow   = ipw + (long)Ll * 3 * Dd * Dd;
    ushort_t* wihb  = aow + (long)Ll * Dd * Dd;
    ushort_t* wsumb = wihb + (long)Ll * 4 * Dd * Dd;
    ushort_t* ff1b  = wsumb + (long)Ll * 4 * Dd * Dd;
    ushort_t* ff2b  = ff1b + (long)Ll * Pp * Dd;
    ushort_t* hwb   = ff2b + (long)Ll * Dd * Pp;

    // ---- one-time weight conversions (per launch) ----
    cvt_k<<<(Ll * 3 * Dd * Dd) / 1024, 256, 0, stream>>>(in_proj_w, ipw);
    cvt_k<<<(Ll * Dd * Dd) / 1024, 256, 0, stream>>>(attn_out_w, aow);
    cvt_k<<<(Ll * 4 * Dd * Dd) / 1024, 256, 0, stream>>>(lstm_wih, wihb);
    cvtadd_k<<<(Ll * 4 * Dd * Dd) / 1024, 256, 0, stream>>>(lstm_wih, lstm_whh, wsumb);
    cvt_k<<<(Ll * Pp * Dd) / 1024, 256, 0, stream>>>(ff_w1, ff1b);
    cvt_k<<<(Ll * Dd * Pp) / 1024, 256, 0, stream>>>(ff_w2, ff2b);
    cvt_k<<<(Vv * Dd) / 1024, 256, 0, stream>>>(head_w, hwb);

    embed_k<<<Tt, 128, 0, stream>>>(tokens, emb, X, Xb);

    for (int l = 0; l < Ll; ++l) {
        // --- attention ---
        gemm_bf16<64, 64, 64, 0, 0><<<dim3(3 * Dd / 64, Tt / 64), 256, 0, stream>>>(
            Xb, ipw + (long)l * 3 * Dd * Dd, in_proj_b + (long)l * 3 * Dd, nullptr,
            BIG, nullptr, Tt, 3 * Dd, Dd);
        attn_k<<<Bb * Hh * Ss, 64, 0, stream>>>(BIG, Tab);
        gemm_bf16<64, 64, 64, 0, 0><<<dim3(Dd / 64, Tt / 64), 256, 0, stream>>>(
            Tab, aow + (long)l * Dd * Dd, attn_out_b + (long)l * Dd, nullptr,
            Tb, nullptr, Tt, Dd, Dd);
        add_ln_k<<<Tt, 256, 0, stream>>>(X, Xb, X, Tb,
                                         ln1_w + (long)l * Dd, ln1_b + (long)l * Dd);

        // --- LSTM latent recurrence (latent==h after step 1 -> wsum folding) ---
        const float* bih = lstm_bih + (long)l * 4 * Dd;
        const float* bhh = lstm_bhh + (long)l * 4 * Dd;
        gemm_bf16<64, 64, 64, 0, 0><<<dim3(4 * Dd / 64, Tt / 64), 256, 0, stream>>>(
            Xb, wihb + (long)l * 4 * Dd * Dd, bih, bhh, BIG, nullptr, Tt, 4 * Dd, Dd);
        lstm_ew_k<<<(Tt * Dd) / 256, 256, 0, stream>>>(BIG, Hb, Hbb, Cb, 1);
        for (int s = 1; s < STEPS; ++s) {
            gemm_bf16<64, 64, 64, 0, 0><<<dim3(4 * Dd / 64, Tt / 64), 256, 0, stream>>>(
                Hbb, wsumb + (long)l * 4 * Dd * Dd, bih, bhh, BIG, nullptr, Tt, 4 * Dd, Dd);
            lstm_ew_k<<<(Tt * Dd) / 256, 256, 0, stream>>>(BIG, Hb, Hbb, Cb, 0);
        }
        add_k<<<(int)(TD / 4 / 256), 256, 0, stream>>>(LAT, LATb, X, Hb);

        // --- feed forward ---
        gemm_bf16<64, 64, 64, 1, 1><<<dim3(Pp / 64, Tt / 64), 256, 0, stream>>>(
            LATb, ff1b + (long)l * Pp * Dd, ff_b1 + (long)l * Pp, nullptr,
            nullptr, BIGb, Tt, Pp, Dd);
        gemm_bf16<64, 64, 64, 0, 0><<<dim3(Dd / 64, Tt / 64), 256, 0, stream>>>(
            BIGb, ff2b + (long)l * Dd * Pp, ff_b2 + (long)l * Dd, nullptr,
            Ta, nullptr, Tt, Dd, Pp);
        add_ln_k<<<Tt, 256, 0, stream>>>(X, Xb, LAT, Ta,
                                         ln2_w + (long)l * Dd, ln2_b + (long)l * Dd);
    }

    // --- head: M=1024, N=32768, K=512 -> 128x128 tile, 2048 blocks ---
    gemm_bf16<128, 128, 32, 0, 0><<<dim3(Vv / 128, Tt / 128), 256, 0, stream>>>(
        Xb, hwb, head_bias, nullptr, out, nullptr, Tt, Vv, Dd);
}